// Round 1
// baseline (732.469 us; speedup 1.0000x reference)
//
#include <hip/hip_runtime.h>
#include <stdint.h>

#define TOKENS 2048
#define HDIM 1024
#define FDIM 3584
#define NEXP 8

#define BM 128
#define BN 64
#define BK 32

typedef __attribute__((ext_vector_type(8))) short short8;
typedef __attribute__((ext_vector_type(4))) float floatx4;

__device__ __forceinline__ unsigned short f2bf(float f) {
  union { float f; unsigned int u; } c; c.f = f;
  unsigned int u = c.u;
  u += 0x7fffu + ((u >> 16) & 1u);   // RTNE
  return (unsigned short)(u >> 16);
}

// ---------------- gating: logits, top-2, softmax, counts ----------------
__global__ void gate_kernel(const float* __restrict__ x,
                            const float* __restrict__ gw,
                            int* __restrict__ top_e,
                            float* __restrict__ top_w,
                            int* __restrict__ count) {
  int wv = threadIdx.x >> 6;
  int lane = threadIdx.x & 63;
  int t = blockIdx.x * 4 + wv;
  if (t >= TOKENS) return;
  float p[NEXP];
#pragma unroll
  for (int e = 0; e < NEXP; e++) p[e] = 0.f;
  const float* xr = x + (size_t)t * HDIM;
  for (int h = lane; h < HDIM; h += 64) {
    float xv = xr[h];
    const float4* g4 = (const float4*)(gw + (size_t)h * NEXP);
    float4 a = g4[0], b = g4[1];
    p[0] += xv * a.x; p[1] += xv * a.y; p[2] += xv * a.z; p[3] += xv * a.w;
    p[4] += xv * b.x; p[5] += xv * b.y; p[6] += xv * b.z; p[7] += xv * b.w;
  }
#pragma unroll
  for (int e = 0; e < NEXP; e++) {
#pragma unroll
    for (int off = 32; off > 0; off >>= 1) p[e] += __shfl_xor(p[e], off, 64);
  }
  if (lane == 0) {
    int i0 = 0;
    for (int e = 1; e < NEXP; e++) if (p[e] > p[i0]) i0 = e;       // first-max tie-break == jax
    int i1 = (i0 == 0) ? 1 : 0;
    for (int e = 0; e < NEXP; e++) if (e != i0 && p[e] > p[i1]) i1 = e;
    float l0 = p[i0], l1 = p[i1];
    float e1 = __expf(l1 - l0);
    float s = 1.f + e1;
    top_e[t * 2] = i0; top_e[t * 2 + 1] = i1;
    top_w[t * 2] = 1.f / s; top_w[t * 2 + 1] = e1 / s;
    atomicAdd(&count[i0], 1);
    atomicAdd(&count[i1], 1);
  }
}

__global__ void offsets_kernel(const int* __restrict__ count,
                               int* __restrict__ offs,
                               int* __restrict__ cursor) {
  if (threadIdx.x == 0 && blockIdx.x == 0) {
    int o = 0;
    for (int e = 0; e < NEXP; e++) { offs[e] = o; cursor[e] = o; o += count[e]; }
  }
}

__global__ void scatter_kernel(const int* __restrict__ top_e,
                               int* __restrict__ cursor,
                               int* __restrict__ tok_of,
                               int* __restrict__ slot_of) {
  int t = blockIdx.x * blockDim.x + threadIdx.x;
  if (t >= TOKENS) return;
#pragma unroll
  for (int k = 0; k < 2; k++) {
    int e = top_e[t * 2 + k];
    int g = atomicAdd(&cursor[e], 1);
    tok_of[g] = t;
    slot_of[t * 2 + k] = g;
  }
}

// ---------------- x fp32 -> bf16 ----------------
__global__ void xconv_kernel(const float* __restrict__ x,
                             unsigned short* __restrict__ xbf) {
  int i = (blockIdx.x * blockDim.x + threadIdx.x) * 4;
  float4 v = *(const float4*)(x + i);
  uint2 pk;
  pk.x = f2bf(v.x) | ((unsigned)f2bf(v.y) << 16);
  pk.y = f2bf(v.z) | ((unsigned)f2bf(v.w) << 16);
  *(uint2*)(xbf + i) = pk;
}

// ---------------- GEMM1: h = X w1^T, g = X w3^T, act = silu(h)*g ----------------
__global__ __launch_bounds__(256, 2)
void gemm1_kernel(const unsigned short* __restrict__ xbf,
                  const float* __restrict__ w1,
                  const float* __restrict__ w3,
                  const int* __restrict__ count,
                  const int* __restrict__ offs,
                  const int* __restrict__ tok_of,
                  unsigned short* __restrict__ act) {
  int e = blockIdx.z;
  int cnt = count[e];
  int m0 = blockIdx.y * BM;
  if (m0 >= cnt) return;
  int f0 = blockIdx.x * BN;
  int off_e = offs[e];

  __shared__ unsigned short sA[BM][BK];
  __shared__ unsigned short sB1[BN][BK];
  __shared__ unsigned short sB3[BN][BK];

  int tid = threadIdx.x;
  int arow = tid >> 1, ahalf = tid & 1;
  int aslot = m0 + arow;
  bool avalid = aslot < cnt;
  int atok = avalid ? tok_of[off_e + aslot] : 0;
  const unsigned short* aptr = xbf + (size_t)atok * HDIM + ahalf * 16;

  int brow = tid >> 2, bseg = tid & 3;
  const float* b1p = w1 + ((size_t)e * FDIM + f0 + brow) * HDIM + bseg * 8;
  const float* b3p = w3 + ((size_t)e * FDIM + f0 + brow) * HDIM + bseg * 8;

  int lane = tid & 63, wv = tid >> 6;
  int lrow = lane & 15, quad = lane >> 4;
  int mbase = wv * 32;

  floatx4 acc1[2][4], acc3[2][4];
#pragma unroll
  for (int i = 0; i < 2; i++)
#pragma unroll
    for (int j = 0; j < 4; j++) {
      acc1[i][j] = (floatx4){0.f, 0.f, 0.f, 0.f};
      acc3[i][j] = (floatx4){0.f, 0.f, 0.f, 0.f};
    }

  for (int k0 = 0; k0 < HDIM; k0 += BK) {
    uint4 av0, av1;
    if (avalid) {
      const uint4* s = (const uint4*)(aptr + k0);
      av0 = s[0]; av1 = s[1];
    } else {
      av0.x = av0.y = av0.z = av0.w = 0u; av1 = av0;
    }
    const float4* s1 = (const float4*)(b1p + k0);
    float4 u1 = s1[0], v1 = s1[1];
    const float4* s3 = (const float4*)(b3p + k0);
    float4 u3 = s3[0], v3 = s3[1];
    uint4 p1, p3;
    p1.x = f2bf(u1.x) | ((unsigned)f2bf(u1.y) << 16);
    p1.y = f2bf(u1.z) | ((unsigned)f2bf(u1.w) << 16);
    p1.z = f2bf(v1.x) | ((unsigned)f2bf(v1.y) << 16);
    p1.w = f2bf(v1.z) | ((unsigned)f2bf(v1.w) << 16);
    p3.x = f2bf(u3.x) | ((unsigned)f2bf(u3.y) << 16);
    p3.y = f2bf(u3.z) | ((unsigned)f2bf(u3.w) << 16);
    p3.z = f2bf(v3.x) | ((unsigned)f2bf(v3.y) << 16);
    p3.w = f2bf(v3.z) | ((unsigned)f2bf(v3.w) << 16);

    *(uint4*)&sA[arow][ahalf * 16] = av0;
    *(uint4*)&sA[arow][ahalf * 16 + 8] = av1;
    *(uint4*)&sB1[brow][bseg * 8] = p1;
    *(uint4*)&sB3[brow][bseg * 8] = p3;
    __syncthreads();

    short8 af[2], b1f[4], b3f[4];
#pragma unroll
    for (int ms = 0; ms < 2; ms++)
      af[ms] = *(const short8*)&sA[mbase + ms * 16 + lrow][quad * 8];
#pragma unroll
    for (int ns = 0; ns < 4; ns++) {
      b1f[ns] = *(const short8*)&sB1[ns * 16 + lrow][quad * 8];
      b3f[ns] = *(const short8*)&sB3[ns * 16 + lrow][quad * 8];
    }
#pragma unroll
    for (int ms = 0; ms < 2; ms++)
#pragma unroll
      for (int ns = 0; ns < 4; ns++) {
        acc1[ms][ns] = __builtin_amdgcn_mfma_f32_16x16x32_bf16(af[ms], b1f[ns], acc1[ms][ns], 0, 0, 0);
        acc3[ms][ns] = __builtin_amdgcn_mfma_f32_16x16x32_bf16(af[ms], b3f[ns], acc3[ms][ns], 0, 0, 0);
      }
    __syncthreads();
  }

  // epilogue: act = silu(h) * g, bf16
#pragma unroll
  for (int ms = 0; ms < 2; ms++) {
#pragma unroll
    for (int reg = 0; reg < 4; reg++) {
      int slot = m0 + mbase + ms * 16 + quad * 4 + reg;
      if (slot < cnt) {
        unsigned short* arow_out = act + (size_t)(off_e + slot) * FDIM;
#pragma unroll
        for (int ns = 0; ns < 4; ns++) {
          float h = acc1[ms][ns][reg];
          float g = acc3[ms][ns][reg];
          float a = h / (1.f + __expf(-h)) * g;
          arow_out[f0 + ns * 16 + lrow] = f2bf(a);
        }
      }
    }
  }
}

// ---------------- GEMM2: contrib = act w2^T ----------------
__global__ __launch_bounds__(256, 2)
void gemm2_kernel(const unsigned short* __restrict__ act,
                  const float* __restrict__ w2,
                  const int* __restrict__ count,
                  const int* __restrict__ offs,
                  float* __restrict__ contrib) {
  int e = blockIdx.z;
  int cnt = count[e];
  int m0 = blockIdx.y * BM;
  if (m0 >= cnt) return;
  int h0 = blockIdx.x * BN;
  int off_e = offs[e];

  __shared__ unsigned short sA[BM][BK];
  __shared__ unsigned short sB[BN][BK];

  int tid = threadIdx.x;
  int arow = tid >> 1, ahalf = tid & 1;
  int aslot = m0 + arow;
  bool avalid = aslot < cnt;
  int aslotc = avalid ? aslot : 0;
  const unsigned short* aptr = act + (size_t)(off_e + aslotc) * FDIM + ahalf * 16;

  int brow = tid >> 2, bseg = tid & 3;
  const float* bp = w2 + ((size_t)e * HDIM + h0 + brow) * FDIM + bseg * 8;

  int lane = tid & 63, wv = tid >> 6;
  int lrow = lane & 15, quad = lane >> 4;
  int mbase = wv * 32;

  floatx4 acc[2][4];
#pragma unroll
  for (int i = 0; i < 2; i++)
#pragma unroll
    for (int j = 0; j < 4; j++) acc[i][j] = (floatx4){0.f, 0.f, 0.f, 0.f};

  for (int k0 = 0; k0 < FDIM; k0 += BK) {
    uint4 av0, av1;
    if (avalid) {
      const uint4* s = (const uint4*)(aptr + k0);
      av0 = s[0]; av1 = s[1];
    } else {
      av0.x = av0.y = av0.z = av0.w = 0u; av1 = av0;
    }
    const float4* sb = (const float4*)(bp + k0);
    float4 u = sb[0], v = sb[1];
    uint4 pb;
    pb.x = f2bf(u.x) | ((unsigned)f2bf(u.y) << 16);
    pb.y = f2bf(u.z) | ((unsigned)f2bf(u.w) << 16);
    pb.z = f2bf(v.x) | ((unsigned)f2bf(v.y) << 16);
    pb.w = f2bf(v.z) | ((unsigned)f2bf(v.w) << 16);

    *(uint4*)&sA[arow][ahalf * 16] = av0;
    *(uint4*)&sA[arow][ahalf * 16 + 8] = av1;
    *(uint4*)&sB[brow][bseg * 8] = pb;
    __syncthreads();

    short8 af[2], bf[4];
#pragma unroll
    for (int ms = 0; ms < 2; ms++)
      af[ms] = *(const short8*)&sA[mbase + ms * 16 + lrow][quad * 8];
#pragma unroll
    for (int ns = 0; ns < 4; ns++)
      bf[ns] = *(const short8*)&sB[ns * 16 + lrow][quad * 8];
#pragma unroll
    for (int ms = 0; ms < 2; ms++)
#pragma unroll
      for (int ns = 0; ns < 4; ns++)
        acc[ms][ns] = __builtin_amdgcn_mfma_f32_16x16x32_bf16(af[ms], bf[ns], acc[ms][ns], 0, 0, 0);
    __syncthreads();
  }

#pragma unroll
  for (int ms = 0; ms < 2; ms++) {
#pragma unroll
    for (int reg = 0; reg < 4; reg++) {
      int slot = m0 + mbase + ms * 16 + quad * 4 + reg;
      if (slot < cnt) {
        float* crow = contrib + (size_t)(off_e + slot) * HDIM;
#pragma unroll
        for (int ns = 0; ns < 4; ns++)
          crow[h0 + ns * 16 + lrow] = acc[ms][ns][reg];
      }
    }
  }
}

// ---------------- combine: out[t] = w0*contrib[g0] + w1*contrib[g1] ----------------
__global__ void combine_kernel(const float* __restrict__ contrib,
                               const int* __restrict__ slot_of,
                               const float* __restrict__ top_w,
                               float* __restrict__ out) {
  int t = blockIdx.x;
  int g0 = slot_of[t * 2], g1 = slot_of[t * 2 + 1];
  float w0 = top_w[t * 2], w1 = top_w[t * 2 + 1];
  const float4* c0 = (const float4*)(contrib + (size_t)g0 * HDIM);
  const float4* c1 = (const float4*)(contrib + (size_t)g1 * HDIM);
  float4* o = (float4*)(out + (size_t)t * HDIM);
  for (int i = threadIdx.x; i < HDIM / 4; i += blockDim.x) {
    float4 a = c0[i], b = c1[i];
    float4 r;
    r.x = w0 * a.x + w1 * b.x;
    r.y = w0 * a.y + w1 * b.y;
    r.z = w0 * a.z + w1 * b.z;
    r.w = w0 * a.w + w1 * b.w;
    o[i] = r;
  }
}

// ---------------- launcher ----------------
extern "C" void kernel_launch(void* const* d_in, const int* in_sizes, int n_in,
                              void* d_out, int out_size, void* d_ws, size_t ws_size,
                              hipStream_t stream) {
  const float* x  = (const float*)d_in[0];
  const float* gw = (const float*)d_in[1];
  const float* w1 = (const float*)d_in[2];
  const float* w3 = (const float*)d_in[3];
  const float* w2 = (const float*)d_in[4];
  float* out = (float*)d_out;

  char* ws = (char*)d_ws;
  const size_t XBF_OFF = 0;                          // 2048*1024*2      = 4 MiB
  const size_t ACT_OFF = 4ull * 1024 * 1024;         // 4096*3584*2      = 28 MiB
  const size_t CON_OFF = ACT_OFF + 29360128ull;      // 4096*1024*4      = 16 MiB
  const size_t SML_OFF = CON_OFF + 16777216ull;

  unsigned short* xbf = (unsigned short*)(ws + XBF_OFF);
  unsigned short* act = (unsigned short*)(ws + ACT_OFF);
  float* contrib = (float*)(ws + CON_OFF);
  float* top_w = (float*)(ws + SML_OFF);
  int* top_e   = (int*)(ws + SML_OFF + 16384);
  int* slot_of = (int*)(ws + SML_OFF + 32768);
  int* tok_of  = (int*)(ws + SML_OFF + 49152);
  int* count   = (int*)(ws + SML_OFF + 65536);
  int* offs    = (int*)(ws + SML_OFF + 65536 + 32);
  int* cursor  = (int*)(ws + SML_OFF + 65536 + 64);

  hipMemsetAsync(count, 0, 96, stream);

  gate_kernel<<<TOKENS / 4, 256, 0, stream>>>(x, gw, top_e, top_w, count);
  offsets_kernel<<<1, 64, 0, stream>>>(count, offs, cursor);
  scatter_kernel<<<TOKENS / 256, 256, 0, stream>>>(top_e, cursor, tok_of, slot_of);
  xconv_kernel<<<(TOKENS * HDIM) / (256 * 4), 256, 0, stream>>>(x, xbf);
  gemm1_kernel<<<dim3(FDIM / BN, TOKENS / BM, NEXP), 256, 0, stream>>>(
      xbf, w1, w3, count, offs, tok_of, act);
  gemm2_kernel<<<dim3(HDIM / BN, TOKENS / BM, NEXP), 256, 0, stream>>>(
      act, w2, count, offs, contrib);
  combine_kernel<<<TOKENS, 256, 0, stream>>>(contrib, slot_of, top_w, out);
}

// Round 2
// 708.747 us; speedup vs baseline: 1.0335x; 1.0335x over previous
//
#include <hip/hip_runtime.h>
#include <hip/hip_bf16.h>
#include <stdint.h>

#define TOKENS 2048
#define HDIM 1024
#define FDIM 3584
#define NEXP 8

#define BK 32
#define LDK 40   // BK + 8 shorts pad: fragment reads 2-way (free), stride 80B

typedef __attribute__((ext_vector_type(8))) short short8;
typedef __attribute__((ext_vector_type(4))) float floatx4;

__device__ __forceinline__ unsigned short f2bf(float f) {
  union { float f; unsigned int u; } c; c.f = f;
  unsigned int u = c.u;
  u += 0x7fffu + ((u >> 16) & 1u);   // RTNE
  return (unsigned short)(u >> 16);
}

__device__ __forceinline__ unsigned int pk2bf(float a, float b) {
  __hip_bfloat162 h = __float22bfloat162_rn(make_float2(a, b));
  union { __hip_bfloat162 h; unsigned int u; } c; c.h = h;
  return c.u;
}

// ---------------- gating: logits, top-2, softmax, counts ----------------
__global__ void gate_kernel(const float* __restrict__ x,
                            const float* __restrict__ gw,
                            int* __restrict__ top_e,
                            float* __restrict__ top_w,
                            int* __restrict__ count) {
  int wv = threadIdx.x >> 6;
  int lane = threadIdx.x & 63;
  int t = blockIdx.x * 4 + wv;
  if (t >= TOKENS) return;
  float p[NEXP];
#pragma unroll
  for (int e = 0; e < NEXP; e++) p[e] = 0.f;
  const float* xr = x + (size_t)t * HDIM;
  for (int h = lane; h < HDIM; h += 64) {
    float xv = xr[h];
    const float4* g4 = (const float4*)(gw + (size_t)h * NEXP);
    float4 a = g4[0], b = g4[1];
    p[0] += xv * a.x; p[1] += xv * a.y; p[2] += xv * a.z; p[3] += xv * a.w;
    p[4] += xv * b.x; p[5] += xv * b.y; p[6] += xv * b.z; p[7] += xv * b.w;
  }
#pragma unroll
  for (int e = 0; e < NEXP; e++) {
#pragma unroll
    for (int off = 32; off > 0; off >>= 1) p[e] += __shfl_xor(p[e], off, 64);
  }
  if (lane == 0) {
    int i0 = 0;
    for (int e = 1; e < NEXP; e++) if (p[e] > p[i0]) i0 = e;
    int i1 = (i0 == 0) ? 1 : 0;
    for (int e = 0; e < NEXP; e++) if (e != i0 && p[e] > p[i1]) i1 = e;
    float l0 = p[i0], l1 = p[i1];
    float e1 = __expf(l1 - l0);
    float s = 1.f + e1;
    top_e[t * 2] = i0; top_e[t * 2 + 1] = i1;
    top_w[t * 2] = 1.f / s; top_w[t * 2 + 1] = e1 / s;
    atomicAdd(&count[i0], 1);
    atomicAdd(&count[i1], 1);
  }
}

__global__ void offsets_kernel(const int* __restrict__ count,
                               int* __restrict__ offs,
                               int* __restrict__ cursor) {
  if (threadIdx.x == 0 && blockIdx.x == 0) {
    int o = 0;
    for (int e = 0; e < NEXP; e++) { offs[e] = o; cursor[e] = o; o += count[e]; }
  }
}

__global__ void scatter_kernel(const int* __restrict__ top_e,
                               int* __restrict__ cursor,
                               int* __restrict__ tok_of,
                               int* __restrict__ slot_of) {
  int t = blockIdx.x * blockDim.x + threadIdx.x;
  if (t >= TOKENS) return;
#pragma unroll
  for (int k = 0; k < 2; k++) {
    int e = top_e[t * 2 + k];
    int g = atomicAdd(&cursor[e], 1);
    tok_of[g] = t;
    slot_of[t * 2 + k] = g;
  }
}

// ---------------- x fp32 -> bf16 ----------------
__global__ void xconv_kernel(const float* __restrict__ x,
                             unsigned short* __restrict__ xbf) {
  int i = (blockIdx.x * blockDim.x + threadIdx.x) * 4;
  float4 v = *(const float4*)(x + i);
  uint2 pk;
  pk.x = pk2bf(v.x, v.y);
  pk.y = pk2bf(v.z, v.w);
  *(uint2*)(xbf + i) = pk;
}

// ---------------- GEMM1: act = silu(X w1^T) * (X w3^T), 256x64 tile ----------------
#define G1_BM 256
#define G1_BF 64

__global__ __launch_bounds__(256, 2)
void gemm1_kernel(const unsigned short* __restrict__ xbf,
                  const float* __restrict__ w1,
                  const float* __restrict__ w3,
                  const int* __restrict__ count,
                  const int* __restrict__ offs,
                  const int* __restrict__ tok_of,
                  unsigned short* __restrict__ act) {
  int e = blockIdx.z;
  int cnt = count[e];
  int m0 = blockIdx.y * G1_BM;
  if (m0 >= cnt) return;
  int f0 = blockIdx.x * G1_BF;
  int off_e = offs[e];

  __shared__ __align__(16) unsigned short sA[G1_BM][LDK];
  __shared__ __align__(16) unsigned short sB1[G1_BF][LDK];
  __shared__ __align__(16) unsigned short sB3[G1_BF][LDK];

  int tid = threadIdx.x;
  // A staging: one 32-element row chunk per thread
  int aslot = m0 + tid;
  bool avalid = aslot < cnt;
  int atok = avalid ? tok_of[off_e + aslot] : 0;
  const unsigned short* aptr = xbf + (size_t)atok * HDIM;

  // B staging: frow 0..63, 8 floats per thread per matrix
  int frow = tid >> 2, bseg = tid & 3;
  const float* b1p = w1 + ((size_t)e * FDIM + f0 + frow) * HDIM + bseg * 8;
  const float* b3p = w3 + ((size_t)e * FDIM + f0 + frow) * HDIM + bseg * 8;

  int lane = tid & 63, wv = tid >> 6;
  int lrow = lane & 15, quad = lane >> 4;
  int mbase = wv * 64;

  floatx4 acc1[4][4], acc3[4][4];
#pragma unroll
  for (int i = 0; i < 4; i++)
#pragma unroll
    for (int j = 0; j < 4; j++) {
      acc1[i][j] = (floatx4){0.f, 0.f, 0.f, 0.f};
      acc3[i][j] = (floatx4){0.f, 0.f, 0.f, 0.f};
    }

  uint4 a_r[4];
  float4 b1_r[2], b3_r[2];

  // prefetch k0 = 0
  if (avalid) {
    const uint4* p = (const uint4*)aptr;
    a_r[0] = p[0]; a_r[1] = p[1]; a_r[2] = p[2]; a_r[3] = p[3];
  } else {
    a_r[0].x = a_r[0].y = a_r[0].z = a_r[0].w = 0u;
    a_r[1] = a_r[0]; a_r[2] = a_r[0]; a_r[3] = a_r[0];
  }
  { const float4* p = (const float4*)b1p; b1_r[0] = p[0]; b1_r[1] = p[1]; }
  { const float4* p = (const float4*)b3p; b3_r[0] = p[0]; b3_r[1] = p[1]; }

  for (int k0 = 0; k0 < HDIM; k0 += BK) {
    uint4 pb1, pb3;
    pb1.x = pk2bf(b1_r[0].x, b1_r[0].y); pb1.y = pk2bf(b1_r[0].z, b1_r[0].w);
    pb1.z = pk2bf(b1_r[1].x, b1_r[1].y); pb1.w = pk2bf(b1_r[1].z, b1_r[1].w);
    pb3.x = pk2bf(b3_r[0].x, b3_r[0].y); pb3.y = pk2bf(b3_r[0].z, b3_r[0].w);
    pb3.z = pk2bf(b3_r[1].x, b3_r[1].y); pb3.w = pk2bf(b3_r[1].z, b3_r[1].w);

    __syncthreads();
    *(uint4*)&sA[tid][0]  = a_r[0];
    *(uint4*)&sA[tid][8]  = a_r[1];
    *(uint4*)&sA[tid][16] = a_r[2];
    *(uint4*)&sA[tid][24] = a_r[3];
    *(uint4*)&sB1[frow][bseg * 8] = pb1;
    *(uint4*)&sB3[frow][bseg * 8] = pb3;
    __syncthreads();

    int kn = k0 + BK;
    if (kn < HDIM) {   // prefetch next tile; loads fly during the MFMA section
      if (avalid) {
        const uint4* p = (const uint4*)(aptr + kn);
        a_r[0] = p[0]; a_r[1] = p[1]; a_r[2] = p[2]; a_r[3] = p[3];
      }
      { const float4* p = (const float4*)(b1p + kn); b1_r[0] = p[0]; b1_r[1] = p[1]; }
      { const float4* p = (const float4*)(b3p + kn); b3_r[0] = p[0]; b3_r[1] = p[1]; }
    }

    short8 af[4], bf1[4], bf3[4];
#pragma unroll
    for (int ms = 0; ms < 4; ms++)
      af[ms] = *(const short8*)&sA[mbase + ms * 16 + lrow][quad * 8];
#pragma unroll
    for (int ns = 0; ns < 4; ns++) {
      bf1[ns] = *(const short8*)&sB1[ns * 16 + lrow][quad * 8];
      bf3[ns] = *(const short8*)&sB3[ns * 16 + lrow][quad * 8];
    }
#pragma unroll
    for (int ms = 0; ms < 4; ms++)
#pragma unroll
      for (int ns = 0; ns < 4; ns++) {
        acc1[ms][ns] = __builtin_amdgcn_mfma_f32_16x16x32_bf16(af[ms], bf1[ns], acc1[ms][ns], 0, 0, 0);
        acc3[ms][ns] = __builtin_amdgcn_mfma_f32_16x16x32_bf16(af[ms], bf3[ns], acc3[ms][ns], 0, 0, 0);
      }
  }

  // epilogue: act = silu(h) * g, bf16
#pragma unroll
  for (int ms = 0; ms < 4; ms++) {
#pragma unroll
    for (int reg = 0; reg < 4; reg++) {
      int slot = m0 + mbase + ms * 16 + quad * 4 + reg;
      if (slot < cnt) {
        unsigned short* ar = act + (size_t)(off_e + slot) * FDIM + f0;
#pragma unroll
        for (int ns = 0; ns < 4; ns++) {
          float h = acc1[ms][ns][reg];
          float g = acc3[ms][ns][reg];
          float a = h / (1.f + __expf(-h)) * g;
          ar[ns * 16 + lrow] = f2bf(a);
        }
      }
    }
  }
}

// ---------------- GEMM2: contrib = act w2^T, 128x128 tile ----------------
#define G2_BM 128
#define G2_BN 128

__global__ __launch_bounds__(256, 2)
void gemm2_kernel(const unsigned short* __restrict__ act,
                  const float* __restrict__ w2,
                  const int* __restrict__ count,
                  const int* __restrict__ offs,
                  float* __restrict__ contrib) {
  int e = blockIdx.z;
  int cnt = count[e];
  int m0 = blockIdx.y * G2_BM;
  if (m0 >= cnt) return;
  int h0 = blockIdx.x * G2_BN;
  int off_e = offs[e];

  __shared__ __align__(16) unsigned short sA[G2_BM][LDK];
  __shared__ __align__(16) unsigned short sB[G2_BN][LDK];

  int tid = threadIdx.x;
  int arow = tid >> 1, aseg = tid & 1;
  int aslot = m0 + arow;
  bool avalid = aslot < cnt;
  const unsigned short* aptr =
      act + (size_t)(off_e + (avalid ? aslot : 0)) * FDIM + aseg * 16;

  int hrow = tid >> 1, hseg = tid & 1;
  const float* bp = w2 + ((size_t)e * HDIM + h0 + hrow) * FDIM + hseg * 16;

  int lane = tid & 63, wv = tid >> 6;
  int lrow = lane & 15, quad = lane >> 4;
  int wm = wv >> 1, wn = wv & 1;
  int mbase = wm * 64, nbase = wn * 64;

  floatx4 acc[4][4];
#pragma unroll
  for (int i = 0; i < 4; i++)
#pragma unroll
    for (int j = 0; j < 4; j++) acc[i][j] = (floatx4){0.f, 0.f, 0.f, 0.f};

  uint4 a_r0, a_r1;
  float4 b_r[4];

  if (avalid) {
    const uint4* p = (const uint4*)aptr;
    a_r0 = p[0]; a_r1 = p[1];
  } else {
    a_r0.x = a_r0.y = a_r0.z = a_r0.w = 0u; a_r1 = a_r0;
  }
  { const float4* p = (const float4*)bp;
    b_r[0] = p[0]; b_r[1] = p[1]; b_r[2] = p[2]; b_r[3] = p[3]; }

  for (int k0 = 0; k0 < FDIM; k0 += BK) {
    uint4 pb0, pb1;
    pb0.x = pk2bf(b_r[0].x, b_r[0].y); pb0.y = pk2bf(b_r[0].z, b_r[0].w);
    pb0.z = pk2bf(b_r[1].x, b_r[1].y); pb0.w = pk2bf(b_r[1].z, b_r[1].w);
    pb1.x = pk2bf(b_r[2].x, b_r[2].y); pb1.y = pk2bf(b_r[2].z, b_r[2].w);
    pb1.z = pk2bf(b_r[3].x, b_r[3].y); pb1.w = pk2bf(b_r[3].z, b_r[3].w);

    __syncthreads();
    *(uint4*)&sA[arow][aseg * 16]     = a_r0;
    *(uint4*)&sA[arow][aseg * 16 + 8] = a_r1;
    *(uint4*)&sB[hrow][hseg * 16]     = pb0;
    *(uint4*)&sB[hrow][hseg * 16 + 8] = pb1;
    __syncthreads();

    int kn = k0 + BK;
    if (kn < FDIM) {
      if (avalid) {
        const uint4* p = (const uint4*)(aptr + kn);
        a_r0 = p[0]; a_r1 = p[1];
      }
      const float4* p = (const float4*)(bp + kn);
      b_r[0] = p[0]; b_r[1] = p[1]; b_r[2] = p[2]; b_r[3] = p[3];
    }

    short8 af[4], bf[4];
#pragma unroll
    for (int ms = 0; ms < 4; ms++)
      af[ms] = *(const short8*)&sA[mbase + ms * 16 + lrow][quad * 8];
#pragma unroll
    for (int ns = 0; ns < 4; ns++)
      bf[ns] = *(const short8*)&sB[nbase + ns * 16 + lrow][quad * 8];
#pragma unroll
    for (int ms = 0; ms < 4; ms++)
#pragma unroll
      for (int ns = 0; ns < 4; ns++)
        acc[ms][ns] = __builtin_amdgcn_mfma_f32_16x16x32_bf16(af[ms], bf[ns], acc[ms][ns], 0, 0, 0);
  }

#pragma unroll
  for (int ms = 0; ms < 4; ms++) {
#pragma unroll
    for (int reg = 0; reg < 4; reg++) {
      int slot = m0 + mbase + ms * 16 + quad * 4 + reg;
      if (slot < cnt) {
        float* crow = contrib + (size_t)(off_e + slot) * HDIM + h0 + nbase;
#pragma unroll
        for (int ns = 0; ns < 4; ns++)
          crow[ns * 16 + lrow] = acc[ms][ns][reg];
      }
    }
  }
}

// ---------------- combine ----------------
__global__ void combine_kernel(const float* __restrict__ contrib,
                               const int* __restrict__ slot_of,
                               const float* __restrict__ top_w,
                               float* __restrict__ out) {
  int t = blockIdx.x;
  int g0 = slot_of[t * 2], g1 = slot_of[t * 2 + 1];
  float w0 = top_w[t * 2], w1 = top_w[t * 2 + 1];
  const float4* c0 = (const float4*)(contrib + (size_t)g0 * HDIM);
  const float4* c1 = (const float4*)(contrib + (size_t)g1 * HDIM);
  float4* o = (float4*)(out + (size_t)t * HDIM);
  for (int i = threadIdx.x; i < HDIM / 4; i += blockDim.x) {
    float4 a = c0[i], b = c1[i];
    float4 r;
    r.x = w0 * a.x + w1 * b.x;
    r.y = w0 * a.y + w1 * b.y;
    r.z = w0 * a.z + w1 * b.z;
    r.w = w0 * a.w + w1 * b.w;
    o[i] = r;
  }
}

// ---------------- launcher ----------------
extern "C" void kernel_launch(void* const* d_in, const int* in_sizes, int n_in,
                              void* d_out, int out_size, void* d_ws, size_t ws_size,
                              hipStream_t stream) {
  const float* x  = (const float*)d_in[0];
  const float* gw = (const float*)d_in[1];
  const float* w1 = (const float*)d_in[2];
  const float* w3 = (const float*)d_in[3];
  const float* w2 = (const float*)d_in[4];
  float* out = (float*)d_out;

  char* ws = (char*)d_ws;
  const size_t XBF_OFF = 0;                          // 2048*1024*2      = 4 MiB
  const size_t ACT_OFF = 4ull * 1024 * 1024;         // 4096*3584*2      = 28 MiB
  const size_t CON_OFF = ACT_OFF + 29360128ull;      // 4096*1024*4      = 16 MiB
  const size_t SML_OFF = CON_OFF + 16777216ull;

  unsigned short* xbf = (unsigned short*)(ws + XBF_OFF);
  unsigned short* act = (unsigned short*)(ws + ACT_OFF);
  float* contrib = (float*)(ws + CON_OFF);
  float* top_w = (float*)(ws + SML_OFF);
  int* top_e   = (int*)(ws + SML_OFF + 16384);
  int* slot_of = (int*)(ws + SML_OFF + 32768);
  int* tok_of  = (int*)(ws + SML_OFF + 49152);
  int* count   = (int*)(ws + SML_OFF + 65536);
  int* offs    = (int*)(ws + SML_OFF + 65536 + 32);
  int* cursor  = (int*)(ws + SML_OFF + 65536 + 64);

  hipMemsetAsync(count, 0, 96, stream);

  gate_kernel<<<TOKENS / 4, 256, 0, stream>>>(x, gw, top_e, top_w, count);
  offsets_kernel<<<1, 64, 0, stream>>>(count, offs, cursor);
  scatter_kernel<<<TOKENS / 256, 256, 0, stream>>>(top_e, cursor, tok_of, slot_of);
  xconv_kernel<<<(TOKENS * HDIM) / (256 * 4), 256, 0, stream>>>(x, xbf);
  gemm1_kernel<<<dim3(FDIM / G1_BF, TOKENS / G1_BM, NEXP), 256, 0, stream>>>(
      xbf, w1, w3, count, offs, tok_of, act);
  gemm2_kernel<<<dim3(HDIM / G2_BN, TOKENS / G2_BM, NEXP), 256, 0, stream>>>(
      act, w2, count, offs, contrib);
  combine_kernel<<<TOKENS, 256, 0, stream>>>(contrib, slot_of, top_w, out);
}

// Round 3
// 566.746 us; speedup vs baseline: 1.2924x; 1.2506x over previous
//
#include <hip/hip_runtime.h>
#include <hip/hip_bf16.h>
#include <stdint.h>

#define TOKENS 2048
#define HDIM 1024
#define FDIM 3584
#define NEXP 8
#define BK 32

typedef __attribute__((ext_vector_type(8))) short short8;
typedef __attribute__((ext_vector_type(4))) float floatx4;

#define AS1 __attribute__((address_space(1)))
#define AS3 __attribute__((address_space(3)))

__device__ __forceinline__ void glds16(const void* g, void* l) {
  __builtin_amdgcn_global_load_lds((const AS1 void*)g, (AS3 void*)l, 16, 0, 0);
}

__device__ __forceinline__ unsigned short f2bf(float f) {
  union { float f; unsigned int u; } c; c.f = f;
  unsigned int u = c.u;
  u += 0x7fffu + ((u >> 16) & 1u);
  return (unsigned short)(u >> 16);
}

__device__ __forceinline__ unsigned int pk2bf(float a, float b) {
  __hip_bfloat162 h = __float22bfloat162_rn(make_float2(a, b));
  union { __hip_bfloat162 h; unsigned int u; } c; c.h = h;
  return c.u;
}

__device__ __forceinline__ short8 pack_bf16(float4 c0, float4 c1) {
  union { short8 s; uint4 u; } o;
  o.u.x = pk2bf(c0.x, c0.y); o.u.y = pk2bf(c0.z, c0.w);
  o.u.z = pk2bf(c1.x, c1.y); o.u.w = pk2bf(c1.z, c1.w);
  return o.s;
}

// ---------------- gating ----------------
__global__ void gate_kernel(const float* __restrict__ x,
                            const float* __restrict__ gw,
                            int* __restrict__ top_e,
                            float* __restrict__ top_w,
                            int* __restrict__ count) {
  int wv = threadIdx.x >> 6;
  int lane = threadIdx.x & 63;
  int t = blockIdx.x * 4 + wv;
  if (t >= TOKENS) return;
  float p[NEXP];
#pragma unroll
  for (int e = 0; e < NEXP; e++) p[e] = 0.f;
  const float* xr = x + (size_t)t * HDIM;
  for (int h = lane; h < HDIM; h += 64) {
    float xv = xr[h];
    const float4* g4 = (const float4*)(gw + (size_t)h * NEXP);
    float4 a = g4[0], b = g4[1];
    p[0] += xv * a.x; p[1] += xv * a.y; p[2] += xv * a.z; p[3] += xv * a.w;
    p[4] += xv * b.x; p[5] += xv * b.y; p[6] += xv * b.z; p[7] += xv * b.w;
  }
#pragma unroll
  for (int e = 0; e < NEXP; e++) {
#pragma unroll
    for (int off = 32; off > 0; off >>= 1) p[e] += __shfl_xor(p[e], off, 64);
  }
  if (lane == 0) {
    int i0 = 0;
    for (int e = 1; e < NEXP; e++) if (p[e] > p[i0]) i0 = e;
    int i1 = (i0 == 0) ? 1 : 0;
    for (int e = 0; e < NEXP; e++) if (e != i0 && p[e] > p[i1]) i1 = e;
    float l0 = p[i0], l1 = p[i1];
    float e1 = __expf(l1 - l0);
    float s = 1.f + e1;
    top_e[t * 2] = i0; top_e[t * 2 + 1] = i1;
    top_w[t * 2] = 1.f / s; top_w[t * 2 + 1] = e1 / s;
    atomicAdd(&count[i0], 1);
    atomicAdd(&count[i1], 1);
  }
}

__global__ void offsets_kernel(const int* __restrict__ count,
                               int* __restrict__ offs,
                               int* __restrict__ cursor) {
  if (threadIdx.x == 0 && blockIdx.x == 0) {
    int o = 0;
    for (int e = 0; e < NEXP; e++) { offs[e] = o; cursor[e] = o; o += count[e]; }
  }
}

__global__ void scatter_kernel(const int* __restrict__ top_e,
                               int* __restrict__ cursor,
                               int* __restrict__ tok_of,
                               int* __restrict__ slot_of) {
  int t = blockIdx.x * blockDim.x + threadIdx.x;
  if (t >= TOKENS) return;
#pragma unroll
  for (int k = 0; k < 2; k++) {
    int e = top_e[t * 2 + k];
    int g = atomicAdd(&cursor[e], 1);
    tok_of[g] = t;
    slot_of[t * 2 + k] = g;
  }
}

__global__ void xconv_kernel(const float* __restrict__ x,
                             unsigned short* __restrict__ xbf) {
  int i = (blockIdx.x * blockDim.x + threadIdx.x) * 4;
  float4 v = *(const float4*)(x + i);
  uint2 pk;
  pk.x = pk2bf(v.x, v.y);
  pk.y = pk2bf(v.z, v.w);
  *(uint2*)(xbf + i) = pk;
}

// ---------------- GEMM1: act = silu(X w1^T) * (X w3^T), 128x64 tile ----------------
// A: bf16 via glds, rows 64B (4 chunks), chunk-swizzle s = q ^ ((r>>1)&3)  -> 2-way
// B: fp32 via glds, rows 128B (8 chunks), chunk-swizzle s = g ^ (r&7)      -> 2-way
#define G1_BM 128
#define G1_BF 64

__global__ __launch_bounds__(256, 3)
void gemm1_kernel(const unsigned short* __restrict__ xbf,
                  const float* __restrict__ w1,
                  const float* __restrict__ w3,
                  const int* __restrict__ count,
                  const int* __restrict__ offs,
                  const int* __restrict__ tok_of,
                  unsigned short* __restrict__ act) {
  int e = blockIdx.z;
  int cnt = count[e];
  int m0 = blockIdx.y * G1_BM;
  if (m0 >= cnt) return;
  int f0 = blockIdx.x * G1_BF;
  int off_e = offs[e];

  __shared__ __align__(16) unsigned short sA[G1_BM * 32];  // 8 KB
  __shared__ __align__(16) float sB1[G1_BF * 32];          // 8 KB
  __shared__ __align__(16) float sB3[G1_BF * 32];          // 8 KB

  int tid = threadIdx.x;
  int lane = tid & 63, wv = tid >> 6;

  // staging descriptors (per-lane global ptr, wave-uniform LDS base)
  const unsigned short* ag[2];
  char* alb[2];
  const float* g1p[2]; const float* g3p[2];
  char* blb[2];
#pragma unroll
  for (int p = 0; p < 2; p++) {
    int c = tid + p * 256;
    {
      int row = c >> 2, slot = c & 3;
      int gch = slot ^ ((row >> 1) & 3);
      int r = m0 + row;
      int tok = tok_of[off_e + (r < cnt ? r : 0)];
      ag[p] = xbf + (size_t)tok * HDIM + gch * 8;
      alb[p] = (char*)sA + (wv * 64 + p * 256) * 16;
    }
    {
      int row = c >> 3, slot = c & 7;
      int gch = slot ^ (row & 7);
      g1p[p] = w1 + ((size_t)e * FDIM + f0 + row) * HDIM + gch * 4;
      g3p[p] = w3 + ((size_t)e * FDIM + f0 + row) * HDIM + gch * 4;
      blb[p] = (char*)sB1 + (wv * 64 + p * 256) * 16;   // sB3 at fixed delta
    }
  }
  size_t b3delta = (char*)sB3 - (char*)sB1;

  int lrow = lane & 15, quad = lane >> 4;
  int wm = wv >> 1, wn = wv & 1;

  floatx4 acc1[4][2], acc3[4][2];
#pragma unroll
  for (int i = 0; i < 4; i++)
#pragma unroll
    for (int j = 0; j < 2; j++) {
      acc1[i][j] = (floatx4){0.f, 0.f, 0.f, 0.f};
      acc3[i][j] = (floatx4){0.f, 0.f, 0.f, 0.f};
    }

  for (int k0 = 0; k0 < HDIM; k0 += BK) {
    __syncthreads();   // previous iteration's reads done before overwrite
#pragma unroll
    for (int p = 0; p < 2; p++) {
      glds16(ag[p] + k0, alb[p]);
      glds16(g1p[p] + k0, blb[p]);
      glds16(g3p[p] + k0, blb[p] + b3delta);
    }
    __syncthreads();   // vmcnt(0) drain -> LDS ready

    short8 af[4], b1f[2], b3f[2];
#pragma unroll
    for (int ms = 0; ms < 4; ms++) {
      int r = wm * 64 + ms * 16 + lrow;
      int sl = quad ^ ((r >> 1) & 3);
      af[ms] = *(const short8*)(sA + r * 32 + sl * 8);
    }
#pragma unroll
    for (int ns = 0; ns < 2; ns++) {
      int r = wn * 32 + ns * 16 + lrow;
      int s0 = (2 * quad) ^ (r & 7), s1 = (2 * quad + 1) ^ (r & 7);
      float4 c0 = *(const float4*)(sB1 + r * 32 + s0 * 4);
      float4 c1 = *(const float4*)(sB1 + r * 32 + s1 * 4);
      b1f[ns] = pack_bf16(c0, c1);
      float4 d0 = *(const float4*)(sB3 + r * 32 + s0 * 4);
      float4 d1 = *(const float4*)(sB3 + r * 32 + s1 * 4);
      b3f[ns] = pack_bf16(d0, d1);
    }
#pragma unroll
    for (int ms = 0; ms < 4; ms++)
#pragma unroll
      for (int ns = 0; ns < 2; ns++) {
        acc1[ms][ns] = __builtin_amdgcn_mfma_f32_16x16x32_bf16(af[ms], b1f[ns], acc1[ms][ns], 0, 0, 0);
        acc3[ms][ns] = __builtin_amdgcn_mfma_f32_16x16x32_bf16(af[ms], b3f[ns], acc3[ms][ns], 0, 0, 0);
      }
  }

#pragma unroll
  for (int ms = 0; ms < 4; ms++) {
#pragma unroll
    for (int reg = 0; reg < 4; reg++) {
      int slot = m0 + wm * 64 + ms * 16 + quad * 4 + reg;
      if (slot < cnt) {
        unsigned short* ar = act + (size_t)(off_e + slot) * FDIM + f0 + wn * 32;
#pragma unroll
        for (int ns = 0; ns < 2; ns++) {
          float h = acc1[ms][ns][reg];
          float g = acc3[ms][ns][reg];
          float a = h / (1.f + __expf(-h)) * g;
          ar[ns * 16 + lrow] = f2bf(a);
        }
      }
    }
  }
}

// ---------------- GEMM2: partial[sk] = act w2^T over K-slice, 128x128 tile ----------------
#define G2_BM 128
#define G2_BN 128
#define SPLITK 4
#define G2_KS (FDIM / SPLITK)   // 896

__global__ __launch_bounds__(256, 3)
void gemm2_kernel(const unsigned short* __restrict__ act,
                  const float* __restrict__ w2,
                  const int* __restrict__ count,
                  const int* __restrict__ offs,
                  float* __restrict__ part) {
  int zz = blockIdx.z;
  int e = zz & 7, sk = zz >> 3;
  int cnt = count[e];
  int m0 = blockIdx.y * G2_BM;
  if (m0 >= cnt) return;
  int h0 = blockIdx.x * G2_BN;
  int off_e = offs[e];
  int kb = sk * G2_KS;

  __shared__ __align__(16) unsigned short sA[G2_BM * 32];  // 8 KB
  __shared__ __align__(16) float sB[G2_BN * 32];           // 16 KB

  int tid = threadIdx.x;
  int lane = tid & 63, wv = tid >> 6;

  const unsigned short* ag[2];
  char* alb[2];
#pragma unroll
  for (int p = 0; p < 2; p++) {
    int c = tid + p * 256;
    int row = c >> 2, slot = c & 3;
    int gch = slot ^ ((row >> 1) & 3);
    int r = m0 + row;
    int rr = (r < cnt ? r : 0);
    ag[p] = act + (size_t)(off_e + rr) * FDIM + kb + gch * 8;
    alb[p] = (char*)sA + (wv * 64 + p * 256) * 16;
  }
  const float* bg[4];
  char* blb[4];
#pragma unroll
  for (int p = 0; p < 4; p++) {
    int c = tid + p * 256;
    int row = c >> 3, slot = c & 7;
    int gch = slot ^ (row & 7);
    bg[p] = w2 + ((size_t)e * HDIM + h0 + row) * FDIM + kb + gch * 4;
    blb[p] = (char*)sB + (wv * 64 + p * 256) * 16;
  }

  int lrow = lane & 15, quad = lane >> 4;
  int wm = wv >> 1, wn = wv & 1;

  floatx4 acc[4][4];
#pragma unroll
  for (int i = 0; i < 4; i++)
#pragma unroll
    for (int j = 0; j < 4; j++) acc[i][j] = (floatx4){0.f, 0.f, 0.f, 0.f};

  for (int k0 = 0; k0 < G2_KS; k0 += BK) {
    __syncthreads();
#pragma unroll
    for (int p = 0; p < 2; p++) glds16(ag[p] + k0, alb[p]);
#pragma unroll
    for (int p = 0; p < 4; p++) glds16(bg[p] + k0, blb[p]);
    __syncthreads();

    short8 af[4], bf[4];
#pragma unroll
    for (int ms = 0; ms < 4; ms++) {
      int r = wm * 64 + ms * 16 + lrow;
      int sl = quad ^ ((r >> 1) & 3);
      af[ms] = *(const short8*)(sA + r * 32 + sl * 8);
    }
#pragma unroll
    for (int ns = 0; ns < 4; ns++) {
      int r = wn * 64 + ns * 16 + lrow;
      int s0 = (2 * quad) ^ (r & 7), s1 = (2 * quad + 1) ^ (r & 7);
      float4 c0 = *(const float4*)(sB + r * 32 + s0 * 4);
      float4 c1 = *(const float4*)(sB + r * 32 + s1 * 4);
      bf[ns] = pack_bf16(c0, c1);
    }
#pragma unroll
    for (int ms = 0; ms < 4; ms++)
#pragma unroll
      for (int ns = 0; ns < 4; ns++)
        acc[ms][ns] = __builtin_amdgcn_mfma_f32_16x16x32_bf16(af[ms], bf[ns], acc[ms][ns], 0, 0, 0);
  }

#pragma unroll
  for (int ms = 0; ms < 4; ms++) {
#pragma unroll
    for (int reg = 0; reg < 4; reg++) {
      int slot = m0 + wm * 64 + ms * 16 + quad * 4 + reg;
      if (slot < cnt) {
        float* crow = part + ((size_t)sk * 4096 + off_e + slot) * HDIM + h0 + wn * 64;
#pragma unroll
        for (int ns = 0; ns < 4; ns++)
          crow[ns * 16 + lrow] = acc[ms][ns][reg];
      }
    }
  }
}

// ---------------- combine: out[t] = sum_k w_k * sum_sk part[sk][g_k] ----------------
__global__ void combine_kernel(const float* __restrict__ part,
                               const int* __restrict__ slot_of,
                               const float* __restrict__ top_w,
                               float* __restrict__ out) {
  int t = blockIdx.x;
  int g0 = slot_of[t * 2], g1 = slot_of[t * 2 + 1];
  float w0 = top_w[t * 2], w1 = top_w[t * 2 + 1];
  int i = threadIdx.x;   // 256 threads x float4 = 1024 floats
  float4 s0 = {0.f, 0.f, 0.f, 0.f}, s1 = {0.f, 0.f, 0.f, 0.f};
#pragma unroll
  for (int sk = 0; sk < SPLITK; sk++) {
    float4 a = ((const float4*)(part + ((size_t)sk * 4096 + g0) * HDIM))[i];
    float4 b = ((const float4*)(part + ((size_t)sk * 4096 + g1) * HDIM))[i];
    s0.x += a.x; s0.y += a.y; s0.z += a.z; s0.w += a.w;
    s1.x += b.x; s1.y += b.y; s1.z += b.z; s1.w += b.w;
  }
  float4 r;
  r.x = w0 * s0.x + w1 * s1.x;
  r.y = w0 * s0.y + w1 * s1.y;
  r.z = w0 * s0.z + w1 * s1.z;
  r.w = w0 * s0.w + w1 * s1.w;
  ((float4*)(out + (size_t)t * HDIM))[i] = r;
}

// ---------------- launcher ----------------
extern "C" void kernel_launch(void* const* d_in, const int* in_sizes, int n_in,
                              void* d_out, int out_size, void* d_ws, size_t ws_size,
                              hipStream_t stream) {
  const float* x  = (const float*)d_in[0];
  const float* gw = (const float*)d_in[1];
  const float* w1 = (const float*)d_in[2];
  const float* w3 = (const float*)d_in[3];
  const float* w2 = (const float*)d_in[4];
  float* out = (float*)d_out;

  char* ws = (char*)d_ws;
  const size_t XBF_OFF = 0;                       // 4 MiB
  const size_t ACT_OFF = 4ull << 20;              // 28 MiB used
  const size_t PART_OFF = 36ull << 20;            // 64 MiB (4 x 4096 x 1024 fp32)
  const size_t SML_OFF = 100ull << 20;

  unsigned short* xbf = (unsigned short*)(ws + XBF_OFF);
  unsigned short* act = (unsigned short*)(ws + ACT_OFF);
  float* part = (float*)(ws + PART_OFF);
  float* top_w = (float*)(ws + SML_OFF);
  int* top_e   = (int*)(ws + SML_OFF + 16384);
  int* slot_of = (int*)(ws + SML_OFF + 32768);
  int* tok_of  = (int*)(ws + SML_OFF + 49152);
  int* count   = (int*)(ws + SML_OFF + 65536);
  int* offs    = (int*)(ws + SML_OFF + 65536 + 32);
  int* cursor  = (int*)(ws + SML_OFF + 65536 + 64);

  hipMemsetAsync(count, 0, 96, stream);

  gate_kernel<<<TOKENS / 4, 256, 0, stream>>>(x, gw, top_e, top_w, count);
  offsets_kernel<<<1, 64, 0, stream>>>(count, offs, cursor);
  scatter_kernel<<<TOKENS / 256, 256, 0, stream>>>(top_e, cursor, tok_of, slot_of);
  xconv_kernel<<<(TOKENS * HDIM) / (256 * 4), 256, 0, stream>>>(x, xbf);
  gemm1_kernel<<<dim3(FDIM / G1_BF, TOKENS / G1_BM, NEXP), 256, 0, stream>>>(
      xbf, w1, w3, count, offs, tok_of, act);
  gemm2_kernel<<<dim3(HDIM / G2_BN, TOKENS / G2_BM, NEXP * SPLITK), 256, 0, stream>>>(
      act, w2, count, offs, part);
  combine_kernel<<<TOKENS, 256, 0, stream>>>(part, slot_of, top_w, out);
}